// Round 16
// baseline (305.434 us; speedup 1.0000x reference)
//
#include <hip/hip_runtime.h>
#include <hip/hip_bf16.h>

#define NN 8192
#define F 64
#define ALPHA 0.2f
#define L2E 1.44269504f
#define DBOUND 16.0f
#define G 8
#define COLS (NN / G)        // 1024
#define NSTEPS (COLS / 32)   // 32
#define NMASKB 2048          // mask blocks in merged kernel

typedef __attribute__((ext_vector_type(8))) short short8;
typedef __attribute__((ext_vector_type(4))) float f32x4;
typedef __attribute__((ext_vector_type(4))) int i32x4;

__device__ __forceinline__ unsigned fb(float x) {
    return __builtin_bit_cast(unsigned, x);
}
__device__ __forceinline__ short f2bf(float x) {
    union { float f; unsigned u; } v; v.f = x;
    unsigned r = v.u + 0x7FFF + ((v.u >> 16) & 1);
    return (short)(r >> 16);
}

// Kernel 0: MERGED mask + prep, MASK FIRST in blockIdx order so the 41-us
// HBM stream fills the machine immediately; prep blocks ride behind.
//   blocks [0, 2048):        mask — adj (256MB) -> bitmask (8MB), wave-linear
//                            16B/lane NT loads (measured 6.2 TB/s)
//   blocks [2048, 4096):     prep — Wh=h@W^T, WhTt (fragment order, direct),
//                            src, dst2=(Wh@a2)*log2e
__global__ __launch_bounds__(256) void k_mp(const float* __restrict__ h,
        const float* __restrict__ W, const float* __restrict__ a,
        const int* __restrict__ adj,
        short* __restrict__ WhTt, float* __restrict__ src,
        float* __restrict__ dst2, unsigned long long* __restrict__ mg) {
    __shared__ float Wl[F][F + 1];
    __shared__ short shT[F][4];
    int tid = threadIdx.x;

    if (blockIdx.x < NMASKB) {
        // ---- mask half (dispatched first) ----
        int w = tid >> 6, l = tid & 63;
        int gw = blockIdx.x * 4 + w;
        const int NW = NMASKB * 4;
        const int NCH = (NN * NN) / 256;          // 262144 chunks of 1 KB
        int sh = 4 * (l & 15);
        #pragma unroll 4
        for (int c = gw; c < NCH; c += NW) {
            size_t base = (size_t)c * 256;
            i32x4 av = __builtin_nontemporal_load((const i32x4*)(adj + base) + l);
            unsigned n = (av.x > 0 ? 1u : 0u) | (av.y > 0 ? 2u : 0u)
                       | (av.z > 0 ? 4u : 0u) | (av.w > 0 ? 8u : 0u);
            unsigned long long v = (unsigned long long)n << sh;
            v |= __shfl_xor(v, 1);
            v |= __shfl_xor(v, 2);
            v |= __shfl_xor(v, 4);
            v |= __shfl_xor(v, 8);
            if ((l & 15) == 0)
                mg[base / 64 + (l >> 4)] = v;
        }
        return;
    }

    // ---- prep half ----
    int b = blockIdx.x - NMASKB;                  // 0..2047
    for (int m = 0; m < 4; ++m) {
        int idx = m * 1024 + tid * 4;
        float4 v = *(const float4*)&W[idx];
        int row = idx >> 6, col = idx & 63;
        Wl[row][col] = v.x; Wl[row][col + 1] = v.y;
        Wl[row][col + 2] = v.z; Wl[row][col + 3] = v.w;
    }
    __syncthreads();
    int w = tid >> 6, lane = tid & 63;
    int i = b * 4 + w;
    const float* hrow = &h[(size_t)i * F];
    float wh = 0.f;
    #pragma unroll
    for (int k = 0; k < F; k += 4) {
        float4 hv = *(const float4*)&hrow[k];
        wh += hv.x * Wl[lane][k] + hv.y * Wl[lane][k + 1]
            + hv.z * Wl[lane][k + 2] + hv.w * Wl[lane][k + 3];
    }
    shT[lane][w] = f2bf(wh);
    float s1 = wh * a[lane];
    float s2 = wh * a[F + lane];
    #pragma unroll
    for (int off = 32; off; off >>= 1) {
        s1 += __shfl_xor(s1, off);
        s2 += __shfl_xor(s2, off);
    }
    if (lane == 0) { src[i] = s1; dst2[i] = s2 * L2E; }
    __syncthreads();
    if (tid < F) {
        // direct fragment-order write (R14-verified index algebra)
        int f = tid;
        int t = b >> 3;
        int off = (b * 4) & 31;
        size_t addr = (((size_t)(t * 4 + (f >> 4)) * 64
                       + (off >> 3) * 16 + (f & 15)) << 3) + (off & 7);
        short4 v = make_short4(shT[f][0], shT[f][1], shT[f][2], shT[f][3]);
        *(short4*)&WhTt[addr] = v;
    }
}

// Kernel B: fused masked-softmax attention (R15 barrier-free loop) + folded
// final reduction: the LAST block per row-block (device-scope atomic ctr)
// sums the G partials, normalizes, applies ELU, writes d_out.
__global__ __launch_bounds__(256, 4) void k_attn(const unsigned* __restrict__ maskg,
        const short8* __restrict__ WhTt, const float* __restrict__ src,
        const float* __restrict__ dst2,
        float* __restrict__ Opart, float* __restrict__ lpart,
        int* __restrict__ ctr, float* __restrict__ out) {
    __shared__ unsigned mlds[64][33];     // 64 rows x 32 mask dwords (+1 pad)
    __shared__ float dlds[COLS];          // dst2 slice
    __shared__ int islast;
    __shared__ float linv[64];

    int rb = blockIdx.x / G;
    int g  = blockIdx.x % G;
    int jbase = g * COLS;
    int tid = threadIdx.x;

    for (int idx = tid; idx < 64 * (COLS / 32); idx += 256) {
        int rr = idx >> 5, cc = idx & 31;
        mlds[rr][cc] = maskg[(size_t)(rb * 64 + rr) * (NN / 32) + (jbase >> 5) + cc];
    }
    for (int idx = tid; idx < COLS; idx += 256)
        dlds[idx] = dst2[jbase + idx];
    __syncthreads();

    int w = tid >> 6, lane = tid & 63;
    int r = lane & 15, q = lane >> 4;
    int qs = q * 8;
    int i = rb * 64 + w * 16 + r;

    float srcv = src[i];
    float sM = srcv + DBOUND;
    float Mi = fmaxf(sM, ALPHA * sM);
    float sL  = srcv * L2E;
    float MiL = Mi * L2E;
    float C1 = sL - MiL;
    float C2 = fmaf(sL, ALPHA, -MiL);

    f32x4 acc0{}, acc1{}, acc2{}, acc3{}, acc4{};
    short8 ones;
    #pragma unroll
    for (int k = 0; k < 8; ++k) ones[k] = (short)0x3F80;  // bf16 1.0

    const unsigned* mrow = &mlds[w * 16 + r][0];

#define LDB(tt, B0, B1, B2, B3) { \
    const short8* bp = WhTt + (size_t)(g * 32 + (tt)) * 256; \
    B0 = bp[lane]; B1 = bp[64 + lane]; B2 = bp[128 + lane]; B3 = bp[192 + lane]; }

#define PEL(dv, bit, eo) { \
    float t1 = (dv) + C1; \
    float t2 = fmaf((dv), ALPHA, C2); \
    float e = __builtin_amdgcn_exp2f(fmaxf(t1, t2)); \
    eo = (bit) ? e : 0.0f; }

    short8 cb0, cb1, cb2, cb3, nb0, nb1, nb2, nb3;
    LDB(0, cb0, cb1, cb2, cb3)

    #pragma unroll 4
    for (int t = 0; t < NSTEPS; ++t) {
        int tn = (t + 1 < NSTEPS) ? t + 1 : t;
        LDB(tn, nb0, nb1, nb2, nb3)           // in flight over this step

        unsigned m8 = (mrow[t] >> qs) & 0xffu;
        float4 d0 = *(const float4*)&dlds[t * 32 + qs];
        float4 d1 = *(const float4*)&dlds[t * 32 + qs + 4];

        float e0, e1, e2, e3, e4, e5, e6, e7;
        PEL(d0.x, (m8 & 1u),   e0) PEL(d0.y, (m8 & 2u),   e1)
        PEL(d0.z, (m8 & 4u),   e2) PEL(d0.w, (m8 & 8u),   e3)
        PEL(d1.x, (m8 & 16u),  e4) PEL(d1.y, (m8 & 32u),  e5)
        PEL(d1.z, (m8 & 64u),  e6) PEL(d1.w, (m8 & 128u), e7)

        unsigned w0 = __builtin_amdgcn_perm(fb(e1), fb(e0), 0x07060302u);
        unsigned w1 = __builtin_amdgcn_perm(fb(e3), fb(e2), 0x07060302u);
        unsigned w2 = __builtin_amdgcn_perm(fb(e5), fb(e4), 0x07060302u);
        unsigned w3 = __builtin_amdgcn_perm(fb(e7), fb(e6), 0x07060302u);
        short8 af = __builtin_bit_cast(short8, make_uint4(w0, w1, w2, w3));

        acc0 = __builtin_amdgcn_mfma_f32_16x16x32_bf16(af, cb0, acc0, 0, 0, 0);
        acc1 = __builtin_amdgcn_mfma_f32_16x16x32_bf16(af, cb1, acc1, 0, 0, 0);
        acc2 = __builtin_amdgcn_mfma_f32_16x16x32_bf16(af, cb2, acc2, 0, 0, 0);
        acc3 = __builtin_amdgcn_mfma_f32_16x16x32_bf16(af, cb3, acc3, 0, 0, 0);
        acc4 = __builtin_amdgcn_mfma_f32_16x16x32_bf16(af, ones, acc4, 0, 0, 0);

        cb0 = nb0; cb1 = nb1; cb2 = nb2; cb3 = nb3;
    }
#undef PEL
#undef LDB

    // acc4: every column holds the row-sum; C rows = q*4 + reg.
    int ic = rb * 64 + w * 16 + q * 4;
    if (r == 0) {
        #pragma unroll
        for (int reg = 0; reg < 4; ++reg)
            lpart[(size_t)g * NN + ic + reg] = acc4[reg];
    }

    size_t ob = (size_t)g * (size_t)(NN * F);
    #pragma unroll
    for (int reg = 0; reg < 4; ++reg) {
        size_t ro = ob + (size_t)(ic + reg) * F + r;
        Opart[ro]      = acc0[reg];
        Opart[ro + 16] = acc1[reg];
        Opart[ro + 32] = acc2[reg];
        Opart[ro + 48] = acc3[reg];
    }

    // ---- folded reduction: last block per rb finishes the 64 rows ----
    __threadfence();                      // release (device scope, cross-XCD)
    __syncthreads();                      // all threads' stores + fences done
    if (tid == 0) islast = (atomicAdd(&ctr[rb], 1) == G - 1);
    __syncthreads();
    if (!islast) return;
    __threadfence();                      // acquire

    if (tid < 64) {
        float l = 0.f;
        #pragma unroll
        for (int gg = 0; gg < G; ++gg)
            l += lpart[(size_t)gg * NN + rb * 64 + tid];
        linv[tid] = 1.0f / l;
    }
    __syncthreads();
    for (int k2 = tid; k2 < 64 * F; k2 += 256) {
        int row = k2 >> 6, col = k2 & 63;
        size_t base2 = (size_t)(rb * 64 + row) * F + col;
        float o = 0.f;
        #pragma unroll
        for (int gg = 0; gg < G; ++gg)
            o += Opart[(size_t)gg * (size_t)(NN * F) + base2];
        float hp = o * linv[row];
        out[base2] = hp > 0.f ? hp : __expf(hp) - 1.f;
    }
}

extern "C" void kernel_launch(void* const* d_in, const int* in_sizes, int n_in,
                              void* d_out, int out_size, void* d_ws, size_t ws_size,
                              hipStream_t stream) {
    const float* h  = (const float*)d_in[0];
    const int* adj  = (const int*)d_in[1];
    const float* W  = (const float*)d_in[2];
    const float* a  = (const float*)d_in[3];
    float* out = (float*)d_out;

    char* ws = (char*)d_ws;
    const size_t OFF_WHTT = 0;                       // 1 MB fragment-order WhTt
    const size_t OFF_SRC  = (1u << 20);              // 32 KB
    const size_t OFF_DST  = OFF_SRC + (32u << 10);   // 32 KB
    const size_t OFF_LP   = OFF_DST + (32u << 10);   // 256 KB (G*NN*4)
    const size_t OFF_MASK = OFF_LP + (size_t)G * NN * 4;      // 8 MB bitmask
    const size_t OFF_CTR  = OFF_MASK + (size_t)NN * (NN / 8); // 4 KB ctr
    const size_t OFF_OP   = OFF_CTR + 4096;                   // 16 MB Opart

    short* WhTt  = (short*)(ws + OFF_WHTT);
    float* src   = (float*)(ws + OFF_SRC);
    float* dst2  = (float*)(ws + OFF_DST);
    float* lpart = (float*)(ws + OFF_LP);
    unsigned long long* maskg = (unsigned long long*)(ws + OFF_MASK);
    int*   ctr   = (int*)(ws + OFF_CTR);
    float* Opart = (float*)(ws + OFF_OP);

    hipMemsetAsync(ctr, 0, (NN / 64) * sizeof(int), stream);
    k_mp<<<NMASKB + NN / 4, 256, 0, stream>>>(h, W, a, adj, WhTt, src, dst2, maskg);
    k_attn<<<(NN / 64) * G, 256, 0, stream>>>((const unsigned*)maskg,
                                              (const short8*)WhTt, src, dst2,
                                              Opart, lpart, ctr, out);
}

// Round 17
// 97.444 us; speedup vs baseline: 3.1344x; 3.1344x over previous
//
#include <hip/hip_runtime.h>
#include <hip/hip_bf16.h>

#define NN 8192
#define F 64
#define ALPHA 0.2f
#define L2E 1.44269504f
#define DBOUND 16.0f
#define G 8
#define COLS (NN / G)        // 1024
#define NSTEPS (COLS / 32)   // 32
#define NMASKB 2048          // mask blocks in merged kernel

typedef __attribute__((ext_vector_type(8))) short short8;
typedef __attribute__((ext_vector_type(4))) float f32x4;
typedef __attribute__((ext_vector_type(4))) int i32x4;

__device__ __forceinline__ unsigned fb(float x) {
    return __builtin_bit_cast(unsigned, x);
}
__device__ __forceinline__ short f2bf(float x) {
    union { float f; unsigned u; } v; v.f = x;
    unsigned r = v.u + 0x7FFF + ((v.u >> 16) & 1);
    return (short)(r >> 16);
}

// Kernel 0: MERGED mask + prep, MASK FIRST (proven ~30us in R16): the 41-us
// adj HBM stream fills the machine immediately; prep blocks ride behind.
__global__ __launch_bounds__(256) void k_mp(const float* __restrict__ h,
        const float* __restrict__ W, const float* __restrict__ a,
        const int* __restrict__ adj,
        short* __restrict__ WhTt, float* __restrict__ src,
        float* __restrict__ dst2, unsigned long long* __restrict__ mg) {
    __shared__ float Wl[F][F + 1];
    __shared__ short shT[F][4];
    int tid = threadIdx.x;

    if (blockIdx.x < NMASKB) {
        // ---- mask half (dispatched first) ----
        int w = tid >> 6, l = tid & 63;
        int gw = blockIdx.x * 4 + w;
        const int NW = NMASKB * 4;
        const int NCH = (NN * NN) / 256;          // 262144 chunks of 1 KB
        int sh = 4 * (l & 15);
        #pragma unroll 4
        for (int c = gw; c < NCH; c += NW) {
            size_t base = (size_t)c * 256;
            i32x4 av = __builtin_nontemporal_load((const i32x4*)(adj + base) + l);
            unsigned n = (av.x > 0 ? 1u : 0u) | (av.y > 0 ? 2u : 0u)
                       | (av.z > 0 ? 4u : 0u) | (av.w > 0 ? 8u : 0u);
            unsigned long long v = (unsigned long long)n << sh;
            v |= __shfl_xor(v, 1);
            v |= __shfl_xor(v, 2);
            v |= __shfl_xor(v, 4);
            v |= __shfl_xor(v, 8);
            if ((l & 15) == 0)
                mg[base / 64 + (l >> 4)] = v;
        }
        return;
    }

    // ---- prep half ----
    int b = blockIdx.x - NMASKB;                  // 0..2047
    for (int m = 0; m < 4; ++m) {
        int idx = m * 1024 + tid * 4;
        float4 v = *(const float4*)&W[idx];
        int row = idx >> 6, col = idx & 63;
        Wl[row][col] = v.x; Wl[row][col + 1] = v.y;
        Wl[row][col + 2] = v.z; Wl[row][col + 3] = v.w;
    }
    __syncthreads();
    int w = tid >> 6, lane = tid & 63;
    int i = b * 4 + w;
    const float* hrow = &h[(size_t)i * F];
    float wh = 0.f;
    #pragma unroll
    for (int k = 0; k < F; k += 4) {
        float4 hv = *(const float4*)&hrow[k];
        wh += hv.x * Wl[lane][k] + hv.y * Wl[lane][k + 1]
            + hv.z * Wl[lane][k + 2] + hv.w * Wl[lane][k + 3];
    }
    shT[lane][w] = f2bf(wh);
    float s1 = wh * a[lane];
    float s2 = wh * a[F + lane];
    #pragma unroll
    for (int off = 32; off; off >>= 1) {
        s1 += __shfl_xor(s1, off);
        s2 += __shfl_xor(s2, off);
    }
    if (lane == 0) { src[i] = s1; dst2[i] = s2 * L2E; }
    __syncthreads();
    if (tid < F) {
        // direct fragment-order write (R14-verified index algebra)
        int f = tid;
        int t = b >> 3;
        int off = (b * 4) & 31;
        size_t addr = (((size_t)(t * 4 + (f >> 4)) * 64
                       + (off >> 3) * 16 + (f & 15)) << 3) + (off & 7);
        short4 v = make_short4(shT[f][0], shT[f][1], shT[f][2], shT[f][3]);
        *(short4*)&WhTt[addr] = v;
    }
}

// Kernel B: fused masked-softmax attention (R15 proven structure), with
// DISTANCE-2 register prefetch on the L2 B-fragment stream (covers L2
// latency; +48 VGPR, still 4 waves/SIMD which is grid-limited anyway).
__global__ __launch_bounds__(256, 4) void k_attn(const unsigned* __restrict__ maskg,
        const short8* __restrict__ WhTt, const float* __restrict__ src,
        const float* __restrict__ dst2,
        float* __restrict__ Opart, float* __restrict__ lpart) {
    __shared__ unsigned mlds[64][33];     // 64 rows x 32 mask dwords (+1 pad)
    __shared__ float dlds[COLS];          // dst2 slice

    int rb = blockIdx.x / G;
    int g  = blockIdx.x % G;
    int jbase = g * COLS;
    int tid = threadIdx.x;

    for (int idx = tid; idx < 64 * (COLS / 32); idx += 256) {
        int rr = idx >> 5, cc = idx & 31;
        mlds[rr][cc] = maskg[(size_t)(rb * 64 + rr) * (NN / 32) + (jbase >> 5) + cc];
    }
    for (int idx = tid; idx < COLS; idx += 256)
        dlds[idx] = dst2[jbase + idx];
    __syncthreads();

    int w = tid >> 6, lane = tid & 63;
    int r = lane & 15, q = lane >> 4;
    int qs = q * 8;
    int i = rb * 64 + w * 16 + r;

    float srcv = src[i];
    float sM = srcv + DBOUND;
    float Mi = fmaxf(sM, ALPHA * sM);
    float sL  = srcv * L2E;
    float MiL = Mi * L2E;
    float C1 = sL - MiL;
    float C2 = fmaf(sL, ALPHA, -MiL);

    f32x4 acc0{}, acc1{}, acc2{}, acc3{}, acc4{};
    short8 ones;
    #pragma unroll
    for (int k = 0; k < 8; ++k) ones[k] = (short)0x3F80;  // bf16 1.0

    const unsigned* mrow = &mlds[w * 16 + r][0];

#define LDB(tt, B0, B1, B2, B3) { \
    const short8* bp = WhTt + (size_t)(g * 32 + (tt)) * 256; \
    B0 = bp[lane]; B1 = bp[64 + lane]; B2 = bp[128 + lane]; B3 = bp[192 + lane]; }

#define PEL(dv, bit, eo) { \
    float t1 = (dv) + C1; \
    float t2 = fmaf((dv), ALPHA, C2); \
    float e = __builtin_amdgcn_exp2f(fmaxf(t1, t2)); \
    eo = (bit) ? e : 0.0f; }

    short8 a0, a1, a2, a3;     // current (t)
    short8 b0, b1, b2, b3;     // t+1
    short8 c0, c1, c2, c3;     // t+2
    LDB(0, a0, a1, a2, a3)
    LDB(1, b0, b1, b2, b3)

    #pragma unroll 4
    for (int t = 0; t < NSTEPS; ++t) {
        int tn2 = (t + 2 < NSTEPS) ? t + 2 : NSTEPS - 1;
        LDB(tn2, c0, c1, c2, c3)              // in flight across TWO steps

        unsigned m8 = (mrow[t] >> qs) & 0xffu;
        float4 d0 = *(const float4*)&dlds[t * 32 + qs];
        float4 d1 = *(const float4*)&dlds[t * 32 + qs + 4];

        float e0, e1, e2, e3, e4, e5, e6, e7;
        PEL(d0.x, (m8 & 1u),   e0) PEL(d0.y, (m8 & 2u),   e1)
        PEL(d0.z, (m8 & 4u),   e2) PEL(d0.w, (m8 & 8u),   e3)
        PEL(d1.x, (m8 & 16u),  e4) PEL(d1.y, (m8 & 32u),  e5)
        PEL(d1.z, (m8 & 64u),  e6) PEL(d1.w, (m8 & 128u), e7)

        unsigned w0 = __builtin_amdgcn_perm(fb(e1), fb(e0), 0x07060302u);
        unsigned w1 = __builtin_amdgcn_perm(fb(e3), fb(e2), 0x07060302u);
        unsigned w2 = __builtin_amdgcn_perm(fb(e5), fb(e4), 0x07060302u);
        unsigned w3 = __builtin_amdgcn_perm(fb(e7), fb(e6), 0x07060302u);
        short8 af = __builtin_bit_cast(short8, make_uint4(w0, w1, w2, w3));

        acc0 = __builtin_amdgcn_mfma_f32_16x16x32_bf16(af, a0, acc0, 0, 0, 0);
        acc1 = __builtin_amdgcn_mfma_f32_16x16x32_bf16(af, a1, acc1, 0, 0, 0);
        acc2 = __builtin_amdgcn_mfma_f32_16x16x32_bf16(af, a2, acc2, 0, 0, 0);
        acc3 = __builtin_amdgcn_mfma_f32_16x16x32_bf16(af, a3, acc3, 0, 0, 0);
        acc4 = __builtin_amdgcn_mfma_f32_16x16x32_bf16(af, ones, acc4, 0, 0, 0);

        a0 = b0; a1 = b1; a2 = b2; a3 = b3;
        b0 = c0; b1 = c1; b2 = c2; b3 = c3;
    }
#undef PEL
#undef LDB

    // acc4: every column holds the row-sum; C rows = q*4 + reg.
    int ic = rb * 64 + w * 16 + q * 4;
    if (r == 0) {
        #pragma unroll
        for (int reg = 0; reg < 4; ++reg)
            lpart[(size_t)g * NN + ic + reg] = acc4[reg];
    }

    size_t ob = (size_t)g * (size_t)(NN * F);
    #pragma unroll
    for (int reg = 0; reg < 4; ++reg) {
        size_t ro = ob + (size_t)(ic + reg) * F + r;
        Opart[ro]      = acc0[reg];
        Opart[ro + 16] = acc1[reg];
        Opart[ro + 32] = acc2[reg];
        Opart[ro + 48] = acc3[reg];
    }
}

// Kernel D: out = elu( (sum_g Opart) / (sum_g lpart) )
__global__ __launch_bounds__(256) void k_reduce(const float* __restrict__ Opart,
        const float* __restrict__ lpart, float* __restrict__ out) {
    int idx = blockIdx.x * 256 + threadIdx.x;
    int i = idx >> 6;
    float o = 0.f, l = 0.f;
    #pragma unroll
    for (int g = 0; g < G; ++g) {
        o += Opart[(size_t)g * (NN * F) + idx];
        l += lpart[(size_t)g * NN + i];
    }
    float hp = o / l;
    out[idx] = hp > 0.f ? hp : __expf(hp) - 1.f;
}

extern "C" void kernel_launch(void* const* d_in, const int* in_sizes, int n_in,
                              void* d_out, int out_size, void* d_ws, size_t ws_size,
                              hipStream_t stream) {
    const float* h  = (const float*)d_in[0];
    const int* adj  = (const int*)d_in[1];
    const float* W  = (const float*)d_in[2];
    const float* a  = (const float*)d_in[3];
    float* out = (float*)d_out;

    char* ws = (char*)d_ws;
    const size_t OFF_WHTT = 0;                       // 1 MB fragment-order WhTt
    const size_t OFF_SRC  = (1u << 20);              // 32 KB
    const size_t OFF_DST  = OFF_SRC + (32u << 10);   // 32 KB
    const size_t OFF_LP   = OFF_DST + (32u << 10);   // 256 KB (G*NN*4)
    const size_t OFF_MASK = OFF_LP + (size_t)G * NN * 4;      // 8 MB bitmask
    const size_t OFF_OP   = OFF_MASK + (size_t)NN * (NN / 8); // 16 MB Opart

    short* WhTt  = (short*)(ws + OFF_WHTT);
    float* src   = (float*)(ws + OFF_SRC);
    float* dst2  = (float*)(ws + OFF_DST);
    float* lpart = (float*)(ws + OFF_LP);
    unsigned long long* maskg = (unsigned long long*)(ws + OFF_MASK);
    float* Opart = (float*)(ws + OFF_OP);

    k_mp<<<NMASKB + NN / 4, 256, 0, stream>>>(h, W, a, adj, WhTt, src, dst2, maskg);
    k_attn<<<(NN / 64) * G, 256, 0, stream>>>((const unsigned*)maskg,
                                              (const short8*)WhTt, src, dst2,
                                              Opart, lpart);
    k_reduce<<<(NN * F) / 256, 256, 0, stream>>>(Opart, lpart, out);
}

// Round 18
// 89.680 us; speedup vs baseline: 3.4058x; 1.0866x over previous
//
#include <hip/hip_runtime.h>
#include <hip/hip_bf16.h>

#define NN 8192
#define F 64
#define ALPHA 0.2f
#define L2E 1.44269504f
#define DBOUND 16.0f
#define G 8
#define COLS (NN / G)        // 1024
#define NSTEPS (COLS / 32)   // 32

typedef __attribute__((ext_vector_type(8))) short short8;
typedef __attribute__((ext_vector_type(4))) float f32x4;
typedef __attribute__((ext_vector_type(4))) int i32x4;

__device__ __forceinline__ unsigned fb(float x) {
    return __builtin_bit_cast(unsigned, x);
}
__device__ __forceinline__ short f2bf(float x) {
    union { float f; unsigned u; } v; v.f = x;
    unsigned r = v.u + 0x7FFF + ((v.u >> 16) & 1);
    return (short)(r >> 16);
}

// Kernel A: Wh = h @ W^T (fp32); WhTt written DIRECTLY in MFMA-fragment
// order (R14-verified index algebra); src = Wh@a1; dst2 = (Wh@a2)*log2e.
__global__ __launch_bounds__(256) void k_prep(const float* __restrict__ h,
        const float* __restrict__ W, const float* __restrict__ a,
        short* __restrict__ WhTt, float* __restrict__ src, float* __restrict__ dst2) {
    __shared__ float Wl[F][F + 1];
    __shared__ short shT[F][4];
    int tid = threadIdx.x;
    for (int m = 0; m < 4; ++m) {
        int idx = m * 1024 + tid * 4;
        float4 v = *(const float4*)&W[idx];
        int row = idx >> 6, col = idx & 63;
        Wl[row][col] = v.x; Wl[row][col + 1] = v.y;
        Wl[row][col + 2] = v.z; Wl[row][col + 3] = v.w;
    }
    __syncthreads();
    int w = tid >> 6, lane = tid & 63;
    int i = blockIdx.x * 4 + w;
    const float* hrow = &h[(size_t)i * F];
    float wh = 0.f;
    #pragma unroll
    for (int k = 0; k < F; k += 4) {
        float4 hv = *(const float4*)&hrow[k];
        wh += hv.x * Wl[lane][k] + hv.y * Wl[lane][k + 1]
            + hv.z * Wl[lane][k + 2] + hv.w * Wl[lane][k + 3];
    }
    shT[lane][w] = f2bf(wh);
    float s1 = wh * a[lane];
    float s2 = wh * a[F + lane];
    #pragma unroll
    for (int off = 32; off; off >>= 1) {
        s1 += __shfl_xor(s1, off);
        s2 += __shfl_xor(s2, off);
    }
    if (lane == 0) { src[i] = s1; dst2[i] = s2 * L2E; }
    __syncthreads();
    if (tid < F) {
        int f = tid;
        int b = blockIdx.x;
        int t = b >> 3;
        int off = (b * 4) & 31;
        size_t addr = (((size_t)(t * 4 + (f >> 4)) * 64
                       + (off >> 3) * 16 + (f & 15)) << 3) + (off & 7);
        short4 v = make_short4(shT[f][0], shT[f][1], shT[f][2], shT[f][3]);
        *(short4*)&WhTt[addr] = v;
    }
}

// Kernel M: compress adj (256 MB int32) -> bitmask (8 MB). STANDALONE and
// pure (every coupling attempt degraded the stream). 6.2 TB/s measured.
__global__ __launch_bounds__(256) void k_mask(const int* __restrict__ adj,
                                              unsigned long long* __restrict__ mg) {
    int w = threadIdx.x >> 6, l = threadIdx.x & 63;
    int gw = blockIdx.x * 4 + w;              // global wave id
    const int NW = 2048 * 4;                  // total waves
    const int NCH = (NN * NN) / 256;          // 262144 chunks of 256 ints (1 KB)
    int sh = 4 * (l & 15);
    #pragma unroll 4
    for (int c = gw; c < NCH; c += NW) {
        size_t base = (size_t)c * 256;
        i32x4 a = __builtin_nontemporal_load((const i32x4*)(adj + base) + l);
        unsigned n = (a.x > 0 ? 1u : 0u) | (a.y > 0 ? 2u : 0u)
                   | (a.z > 0 ? 4u : 0u) | (a.w > 0 ? 8u : 0u);
        unsigned long long v = (unsigned long long)n << sh;
        v |= __shfl_xor(v, 1);
        v |= __shfl_xor(v, 2);
        v |= __shfl_xor(v, 4);
        v |= __shfl_xor(v, 8);
        if ((l & 15) == 0)
            mg[base / 64 + (l >> 4)] = v;
    }
}

// Kernel B: fused masked-softmax attention (R15 structure) + register
// prefetch of next step's LDS operands (d0,d1,m8) so no ds_read latency
// sits on the critical path. LDB stays distance-1 (proven).
__global__ __launch_bounds__(256, 4) void k_attn(const unsigned* __restrict__ maskg,
        const short8* __restrict__ WhTt, const float* __restrict__ src,
        const float* __restrict__ dst2,
        float* __restrict__ Opart, float* __restrict__ lpart) {
    __shared__ unsigned mlds[64][33];     // 64 rows x 32 mask dwords (+1 pad)
    __shared__ float dlds[COLS];          // dst2 slice

    int rb = blockIdx.x / G;
    int g  = blockIdx.x % G;
    int jbase = g * COLS;
    int tid = threadIdx.x;

    for (int idx = tid; idx < 64 * (COLS / 32); idx += 256) {
        int rr = idx >> 5, cc = idx & 31;
        mlds[rr][cc] = maskg[(size_t)(rb * 64 + rr) * (NN / 32) + (jbase >> 5) + cc];
    }
    for (int idx = tid; idx < COLS; idx += 256)
        dlds[idx] = dst2[jbase + idx];
    __syncthreads();

    int w = tid >> 6, lane = tid & 63;
    int r = lane & 15, q = lane >> 4;
    int qs = q * 8;
    int i = rb * 64 + w * 16 + r;

    float srcv = src[i];
    float sM = srcv + DBOUND;
    float Mi = fmaxf(sM, ALPHA * sM);
    float sL  = srcv * L2E;
    float MiL = Mi * L2E;
    float C1 = sL - MiL;
    float C2 = fmaf(sL, ALPHA, -MiL);

    f32x4 acc0{}, acc1{}, acc2{}, acc3{}, acc4{};
    short8 ones;
    #pragma unroll
    for (int k = 0; k < 8; ++k) ones[k] = (short)0x3F80;  // bf16 1.0

    const unsigned* mrow = &mlds[w * 16 + r][0];

#define LDB(tt, B0, B1, B2, B3) { \
    const short8* bp = WhTt + (size_t)(g * 32 + (tt)) * 256; \
    B0 = bp[lane]; B1 = bp[64 + lane]; B2 = bp[128 + lane]; B3 = bp[192 + lane]; }

#define PEL(dv, bit, eo) { \
    float t1 = (dv) + C1; \
    float t2 = fmaf((dv), ALPHA, C2); \
    float e = __builtin_amdgcn_exp2f(fmaxf(t1, t2)); \
    eo = (bit) ? e : 0.0f; }

    short8 cb0, cb1, cb2, cb3, nb0, nb1, nb2, nb3;
    LDB(0, cb0, cb1, cb2, cb3)
    // prefetch step-0 LDS operands
    unsigned cm = mrow[0];
    float4 cd0 = *(const float4*)&dlds[qs];
    float4 cd1 = *(const float4*)&dlds[qs + 4];

    #pragma unroll 4
    for (int t = 0; t < NSTEPS; ++t) {
        int tn = (t + 1 < NSTEPS) ? t + 1 : t;
        LDB(tn, nb0, nb1, nb2, nb3)               // L2 stream, dist-1

        // prefetch next step's LDS operands (consumed next iteration)
        unsigned nm = mrow[tn];
        float4 nd0 = *(const float4*)&dlds[tn * 32 + qs];
        float4 nd1 = *(const float4*)&dlds[tn * 32 + qs + 4];

        unsigned m8 = (cm >> qs) & 0xffu;
        float e0, e1, e2, e3, e4, e5, e6, e7;
        PEL(cd0.x, (m8 & 1u),   e0) PEL(cd0.y, (m8 & 2u),   e1)
        PEL(cd0.z, (m8 & 4u),   e2) PEL(cd0.w, (m8 & 8u),   e3)
        PEL(cd1.x, (m8 & 16u),  e4) PEL(cd1.y, (m8 & 32u),  e5)
        PEL(cd1.z, (m8 & 64u),  e6) PEL(cd1.w, (m8 & 128u), e7)

        unsigned w0 = __builtin_amdgcn_perm(fb(e1), fb(e0), 0x07060302u);
        unsigned w1 = __builtin_amdgcn_perm(fb(e3), fb(e2), 0x07060302u);
        unsigned w2 = __builtin_amdgcn_perm(fb(e5), fb(e4), 0x07060302u);
        unsigned w3 = __builtin_amdgcn_perm(fb(e7), fb(e6), 0x07060302u);
        short8 af = __builtin_bit_cast(short8, make_uint4(w0, w1, w2, w3));

        acc0 = __builtin_amdgcn_mfma_f32_16x16x32_bf16(af, cb0, acc0, 0, 0, 0);
        acc1 = __builtin_amdgcn_mfma_f32_16x16x32_bf16(af, cb1, acc1, 0, 0, 0);
        acc2 = __builtin_amdgcn_mfma_f32_16x16x32_bf16(af, cb2, acc2, 0, 0, 0);
        acc3 = __builtin_amdgcn_mfma_f32_16x16x32_bf16(af, cb3, acc3, 0, 0, 0);
        acc4 = __builtin_amdgcn_mfma_f32_16x16x32_bf16(af, ones, acc4, 0, 0, 0);

        cb0 = nb0; cb1 = nb1; cb2 = nb2; cb3 = nb3;
        cm = nm; cd0 = nd0; cd1 = nd1;
    }
#undef PEL
#undef LDB

    // acc4: every column holds the row-sum; C rows = q*4 + reg.
    int ic = rb * 64 + w * 16 + q * 4;
    if (r == 0) {
        #pragma unroll
        for (int reg = 0; reg < 4; ++reg)
            lpart[(size_t)g * NN + ic + reg] = acc4[reg];
    }

    size_t ob = (size_t)g * (size_t)(NN * F);
    #pragma unroll
    for (int reg = 0; reg < 4; ++reg) {
        size_t ro = ob + (size_t)(ic + reg) * F + r;
        Opart[ro]      = acc0[reg];
        Opart[ro + 16] = acc1[reg];
        Opart[ro + 32] = acc2[reg];
        Opart[ro + 48] = acc3[reg];
    }
}

// Kernel D: out = elu( (sum_g Opart) / (sum_g lpart) )
__global__ __launch_bounds__(256) void k_reduce(const float* __restrict__ Opart,
        const float* __restrict__ lpart, float* __restrict__ out) {
    int idx = blockIdx.x * 256 + threadIdx.x;
    int i = idx >> 6;
    float o = 0.f, l = 0.f;
    #pragma unroll
    for (int g = 0; g < G; ++g) {
        o += Opart[(size_t)g * (NN * F) + idx];
        l += lpart[(size_t)g * NN + i];
    }
    float hp = o / l;
    out[idx] = hp > 0.f ? hp : __expf(hp) - 1.f;
}

extern "C" void kernel_launch(void* const* d_in, const int* in_sizes, int n_in,
                              void* d_out, int out_size, void* d_ws, size_t ws_size,
                              hipStream_t stream) {
    const float* h  = (const float*)d_in[0];
    const int* adj  = (const int*)d_in[1];
    const float* W  = (const float*)d_in[2];
    const float* a  = (const float*)d_in[3];
    float* out = (float*)d_out;

    char* ws = (char*)d_ws;
    const size_t OFF_WHTT = 0;                       // 1 MB fragment-order WhTt
    const size_t OFF_SRC  = (1u << 20);              // 32 KB
    const size_t OFF_DST  = OFF_SRC + (32u << 10);   // 32 KB
    const size_t OFF_LP   = OFF_DST + (32u << 10);   // 256 KB (G*NN*4)
    const size_t OFF_MASK = OFF_LP + (size_t)G * NN * 4;      // 8 MB bitmask
    const size_t OFF_OP   = OFF_MASK + (size_t)NN * (NN / 8); // 16 MB Opart

    short* WhTt  = (short*)(ws + OFF_WHTT);
    float* src   = (float*)(ws + OFF_SRC);
    float* dst2  = (float*)(ws + OFF_DST);
    float* lpart = (float*)(ws + OFF_LP);
    unsigned long long* maskg = (unsigned long long*)(ws + OFF_MASK);
    float* Opart = (float*)(ws + OFF_OP);

    k_mask<<<2048, 256, 0, stream>>>(adj, maskg);
    k_prep<<<NN / 4, 256, 0, stream>>>(h, W, a, WhTt, src, dst2);
    k_attn<<<(NN / 64) * G, 256, 0, stream>>>((const unsigned*)maskg,
                                              (const short8*)WhTt, src, dst2,
                                              Opart, lpart);
    k_reduce<<<(NN * F) / 256, 256, 0, stream>>>(Opart, lpart, out);
}